// Round 4
// baseline (539.326 us; speedup 1.0000x reference)
//
#include <hip/hip_runtime.h>
#include <hip/hip_bf16.h>
#include <math.h>

typedef __hip_bfloat16 bf16;
typedef __bf16 bf8v __attribute__((ext_vector_type(8)));
typedef float f4v __attribute__((ext_vector_type(4)));

__device__ inline void storeC(bf16* p, float v) { *p = __float2bfloat16(v); }
__device__ inline void storeC(float* p, float v) { *p = v; }

// async global->LDS, 16B per lane; LDS base must be wave-uniform, HW adds lane*16.
__device__ inline void gld16(const void* g, void* l) {
    __builtin_amdgcn_global_load_lds(
        (__attribute__((address_space(1))) void*)g,
        (__attribute__((address_space(3))) void*)l, 16, 0, 0);
}

// ---------------- fp32 -> bf16 cast (vectorized, n % 1024 == 0) ----------------
__global__ __launch_bounds__(256)
void cast_f2b(const float* __restrict__ X, bf16* __restrict__ Y, long n)
{
    const long i = ((long)blockIdx.x * 256 + threadIdx.x) * 4;
    if (i + 3 < n) {
        const float4 v = *(const float4*)(X + i);
        Y[i + 0] = __float2bfloat16(v.x);
        Y[i + 1] = __float2bfloat16(v.y);
        Y[i + 2] = __float2bfloat16(v.z);
        Y[i + 3] = __float2bfloat16(v.w);
    }
}

// ---------------- GEMM: C[M,N] = epi( A[M,K] @ W[N,K]^T + bias[N] ) ----------------
// A,W bf16; bias,R fp32; C is CT (bf16 or float). ACT: 0 none, 1 exact GELU.
// C may alias R elementwise (each thread reads R[idx] then writes C[idx] once).
// m97 structure: global_load_lds width=16 staging, 2-barrier K-loop.
template<int ACT, bool HASRES, typename CT>
__global__ __launch_bounds__(256)
void gemm_bt(const bf16* __restrict__ A, const bf16* __restrict__ W,
             const float* __restrict__ bias, const float* __restrict__ R,
             CT* __restrict__ C, int M, int N, int K)
{
    __shared__ __align__(16) unsigned short sA[128 * 32];
    __shared__ __align__(16) unsigned short sB[128 * 32];

    const int tid  = threadIdx.x;
    const int lane = tid & 63;
    const int wave = tid >> 6;
    const long row0 = (long)blockIdx.x * 128;
    const long col0 = (long)blockIdx.y * 128;
    const int wm = (wave >> 1) * 64;   // wave's 64-row strip in tile
    const int wn = (wave & 1) * 64;    // wave's 64-col strip in tile
    const int fr = lane & 15;          // fragment row (A) / col (B)
    const int fk = (lane >> 4) * 8;    // fragment k offset

    const f4v fzero = {0.f, 0.f, 0.f, 0.f};
    f4v acc[4][4];
#pragma unroll
    for (int i = 0; i < 4; ++i)
#pragma unroll
        for (int j = 0; j < 4; ++j) acc[i][j] = fzero;

    // staging: thread t owns 16B chunk (row = tid>>2, kc = tid&3), rows +0/+64.
    // (tid>>2)*32 + (tid&3)*8 == tid*8 -> LDS layout is lane-contiguous, matching
    // gld16's wave-uniform-base + lane*16B write pattern.
    const unsigned short* gA = (const unsigned short*)A + (row0 + (tid >> 2)) * (long)K + (tid & 3) * 8;
    const unsigned short* gB = (const unsigned short*)W + (col0 + (tid >> 2)) * (long)K + (tid & 3) * 8;
    unsigned short* lA0 = &sA[wave * 512];
    unsigned short* lA1 = &sA[2048 + wave * 512];
    unsigned short* lB0 = &sB[wave * 512];
    unsigned short* lB1 = &sB[2048 + wave * 512];

    for (int k0 = 0; k0 < K; k0 += 32) {
        gld16(gA + k0,                lA0);
        gld16(gA + 64 * (long)K + k0, lA1);
        gld16(gB + k0,                lB0);
        gld16(gB + 64 * (long)K + k0, lB1);
        __syncthreads();   // drains vmcnt(0): LDS populated, all waves arrived

        bf8v af[4], bv[4];
#pragma unroll
        for (int t = 0; t < 4; ++t) {
            af[t] = *(const bf8v*)&sA[(wm + t * 16 + fr) * 32 + fk];
            bv[t] = *(const bf8v*)&sB[(wn + t * 16 + fr) * 32 + fk];
        }
#pragma unroll
        for (int i = 0; i < 4; ++i)
#pragma unroll
            for (int j = 0; j < 4; ++j)
                acc[i][j] = __builtin_amdgcn_mfma_f32_16x16x32_bf16(af[i], bv[j], acc[i][j], 0, 0, 0);
        __syncthreads();   // all LDS reads done before next iter's gld16 overwrites
    }

    // epilogue: D mapping col = lane&15, row = (lane>>4)*4 + reg  [m89/m91 verified]
#pragma unroll
    for (int j = 0; j < 4; ++j) {
        const long n = col0 + wn + j * 16 + fr;
        const float bvv = bias[n];
#pragma unroll
        for (int i = 0; i < 4; ++i) {
            const long mbase = row0 + wm + i * 16 + (lane >> 4) * 4;
#pragma unroll
            for (int r = 0; r < 4; ++r) {
                float v0 = acc[i][j][r] + bvv;
                if (HASRES) v0 += R[(mbase + r) * (long)N + n];
                if (ACT == 1) v0 = 0.5f * v0 * (1.f + erff(v0 * 0.70710678118654752f));
                storeC(&C[(mbase + r) * (long)N + n], v0);
            }
        }
    }
}

// ---------------- per-position head attention (the einsum quirk) ----------------
// For each (b,j): E = Q_j K_j^T / 32 over heads (16x16), softmax rows, O = A V_j (16x64).
// Store with reshape scramble: scr[b, h*128 + j/16, (j%16)*64 + d] = O[h][d].
__global__ __launch_bounds__(256)
void attn_kernel(const bf16* __restrict__ qkv, bf16* __restrict__ scr)
{
    __shared__ float sb[4][3392];   // per wave: q[16][65], k[16][65], v[16][65], a[16][17]
    const int tid = threadIdx.x;
    const int wave = tid >> 6, lane = tid & 63;
    const int m = blockIdx.x * 4 + wave;       // global position in [0, 8192)

    float* q = sb[wave];
    float* k = q + 1040;
    float* v = k + 1040;
    float* a = v + 1040;

    const bf16* rowp = qkv + (size_t)m * 3072;
    for (int i = lane; i < 1024; i += 64) {
        int hh = i >> 6, dd = i & 63;
        q[hh * 65 + dd] = __bfloat162float(rowp[i]);
        k[hh * 65 + dd] = __bfloat162float(rowp[1024 + i]);
        v[hh * 65 + dd] = __bfloat162float(rowp[2048 + i]);
    }
    __syncthreads();

    // lane -> (h1 = lane&15, quad = lane>>4 owning h2 = quad*4..+3)
    const int h1 = lane & 15, qd = lane >> 4;
    float e[4];
#pragma unroll
    for (int j = 0; j < 4; ++j) {
        const float* qr = q + h1 * 65;
        const float* kr = k + (qd * 4 + j) * 65;
        float s0 = 0.f;
        for (int d = 0; d < 64; ++d) s0 += qr[d] * kr[d];
        e[j] = s0 * 0.03125f;                  // 1/sqrt(1024)
    }
    float mx = fmaxf(fmaxf(e[0], e[1]), fmaxf(e[2], e[3]));
    mx = fmaxf(mx, __shfl_xor(mx, 16, 64));
    mx = fmaxf(mx, __shfl_xor(mx, 32, 64));
    float p[4], ps = 0.f;
#pragma unroll
    for (int j = 0; j < 4; ++j) { p[j] = expf(e[j] - mx); ps += p[j]; }
    ps += __shfl_xor(ps, 16, 64);
    ps += __shfl_xor(ps, 32, 64);
    const float inv = 1.f / ps;
#pragma unroll
    for (int j = 0; j < 4; ++j) a[h1 * 17 + qd * 4 + j] = p[j] * inv;
    __syncthreads();

    // O[h][d] = sum_l a[h][l] * v[l][d]; lane -> (h = lane&15, d in (lane>>4)*16..+16)
    const int h = lane & 15, dg = lane >> 4;
    float arow[16];
#pragma unroll
    for (int l2 = 0; l2 < 16; ++l2) arow[l2] = a[h * 17 + l2];
    const int b = m >> 11, j = m & 2047;
    bf16* op = scr + (((size_t)b * 2048 + h * 128 + (j >> 4)) * 1024 + (j & 15) * 64);
    for (int t = 0; t < 16; ++t) {
        const int d = dg * 16 + t;
        float o = 0.f;
#pragma unroll
        for (int l2 = 0; l2 < 16; ++l2) o += arow[l2] * v[l2 * 65 + d];
        op[d] = __float2bfloat16(o);
    }
}

// -------- row LayerNorm over E=1024, fp32 in, fp32 out (+optional bf16 copy) --------
// In-place safe (X==Y32): all loads precede the first barrier within a block's row.
__global__ __launch_bounds__(256)
void ln_kernel(const float* __restrict__ X, const float* __restrict__ G,
               const float* __restrict__ Bt, float* __restrict__ Y32,
               bf16* __restrict__ Yb)
{
    __shared__ float rs[4], rq[4];
    const int tid = threadIdx.x;
    const long row = blockIdx.x;
    const float* xp = X + row * 1024;
    float x[4];
#pragma unroll
    for (int i = 0; i < 4; ++i) x[i] = xp[tid + 256 * i];

    float s = x[0] + x[1] + x[2] + x[3];
#pragma unroll
    for (int off = 32; off; off >>= 1) s += __shfl_down(s, off, 64);
    if ((tid & 63) == 0) rs[tid >> 6] = s;
    __syncthreads();
    const float mean = (rs[0] + rs[1] + rs[2] + rs[3]) * (1.f / 1024.f);

    float qv = 0.f;
#pragma unroll
    for (int i = 0; i < 4; ++i) { float d = x[i] - mean; qv += d * d; }
#pragma unroll
    for (int off = 32; off; off >>= 1) qv += __shfl_down(qv, off, 64);
    if ((tid & 63) == 0) rq[tid >> 6] = qv;
    __syncthreads();
    const float var = (rq[0] + rq[1] + rq[2] + rq[3]) * (1.f / 1024.f);
    const float rstd = rsqrtf(var + 1e-5f);

#pragma unroll
    for (int i = 0; i < 4; ++i) {
        const int e = tid + 256 * i;
        const float yv = (x[i] - mean) * rstd * G[e] + Bt[e];
        Y32[row * 1024 + e] = yv;
        if (Yb) Yb[row * 1024 + e] = __float2bfloat16(yv);
    }
}

extern "C" void kernel_launch(void* const* d_in, const int* in_sizes, int n_in,
                              void* d_out, int out_size, void* d_ws, size_t ws_size,
                              hipStream_t stream)
{
    (void)in_sizes; (void)n_in; (void)out_size;
    // Reference dtypes are all float32.
    const float* x    = (const float*)d_in[0];
    const float* Wqkv = (const float*)d_in[1];
    const float* bqkv = (const float*)d_in[2];
    const float* Wo   = (const float*)d_in[3];
    const float* bo   = (const float*)d_in[4];
    const float* g1   = (const float*)d_in[5];
    const float* b1   = (const float*)d_in[6];
    const float* W1   = (const float*)d_in[7];
    const float* bf1  = (const float*)d_in[8];
    const float* W2   = (const float*)d_in[9];
    const float* bf2  = (const float*)d_in[10];
    const float* g2   = (const float*)d_in[11];
    const float* b2   = (const float*)d_in[12];
    float* out = (float*)d_out;   // fp32 output, also used as h/s2 scratch

    // If ws is too small, bail -> output stays 0 -> absmax == 5.1875 (diagnostic).
    if (ws_size < 125829120ULL) return;

    // ws layout (bytes):
    //   R1 @0, 67,108,864: qkv bf16(50.3M) -> t fp32(33.5M) -> u bf16(67M)
    //   Wqkvb @67108864 (6.3M) | Wob @73400320 (2.1M) | W1b @75497472 (8.4M)
    //   W2b @83886080 (8.4M)   | xb/scr @92274688 (16.8M) | hb @109051904 (16.8M)
    char* ws = (char*)d_ws;
    bf16* qkv   = (bf16*)(ws + 0);
    float* t    = (float*)(ws + 0);
    bf16* u     = (bf16*)(ws + 0);
    bf16* Wqkvb = (bf16*)(ws + 67108864);
    bf16* Wob   = (bf16*)(ws + 73400320);
    bf16* W1b   = (bf16*)(ws + 75497472);
    bf16* W2b   = (bf16*)(ws + 83886080);
    bf16* xb    = (bf16*)(ws + 92274688);
    bf16* scr   = (bf16*)(ws + 92274688);   // reuses xb (dead after gemm1)
    bf16* hb    = (bf16*)(ws + 109051904);
    float* h    = out;                       // fp32 h lives in d_out until gemm6

    // 0) casts fp32 -> bf16
    cast_f2b<<<8192, 256, 0, stream>>>(x,    xb,    8388608);
    cast_f2b<<<3072, 256, 0, stream>>>(Wqkv, Wqkvb, 3145728);
    cast_f2b<<<1024, 256, 0, stream>>>(Wo,   Wob,   1048576);
    cast_f2b<<<4096, 256, 0, stream>>>(W1,   W1b,   4194304);
    cast_f2b<<<4096, 256, 0, stream>>>(W2,   W2b,   4194304);

    // 1) qkv = x @ Wqkv^T + bqkv            (bf16 out)
    gemm_bt<0, false, bf16><<<dim3(64, 24), 256, 0, stream>>>(xb, Wqkvb, bqkv, nullptr, qkv, 8192, 3072, 1024);
    // 2) per-position head attention + reshape scramble -> scr
    attn_kernel<<<2048, 256, 0, stream>>>(qkv, scr);
    // 3) t = scr @ Wo^T + bo + x            (fp32 out, fp32 residual)
    gemm_bt<0, true, float><<<dim3(64, 8), 256, 0, stream>>>(scr, Wob, bo, x, t, 8192, 1024, 1024);
    // 4) h = LN1(t)  -> fp32 h (d_out) + bf16 hb
    ln_kernel<<<8192, 256, 0, stream>>>(t, g1, b1, h, hb);
    // 5) u = gelu(hb @ W1^T + bf1)          (bf16 out, overwrites R1; t is dead)
    gemm_bt<1, false, bf16><<<dim3(64, 32), 256, 0, stream>>>(hb, W1b, bf1, nullptr, u, 8192, 4096, 1024);
    // 6) s2 = u @ W2^T + bf2 + h            (fp32 out aliasing R=h elementwise in d_out)
    gemm_bt<0, true, float><<<dim3(64, 8), 256, 0, stream>>>(u, W2b, bf2, h, out, 8192, 1024, 4096);
    // 7) out = LN2(s2) in-place, fp32 only
    ln_kernel<<<8192, 256, 0, stream>>>(out, g2, b2, out, nullptr);
}

// Round 5
// 515.043 us; speedup vs baseline: 1.0471x; 1.0471x over previous
//
#include <hip/hip_runtime.h>
#include <hip/hip_bf16.h>
#include <math.h>

typedef __hip_bfloat16 bf16;
typedef __bf16 bf8v __attribute__((ext_vector_type(8)));
typedef float f4v __attribute__((ext_vector_type(4)));
typedef unsigned short us8 __attribute__((ext_vector_type(8)));

__device__ inline void storeC(bf16* p, float v) { *p = __float2bfloat16(v); }
__device__ inline void storeC(float* p, float v) { *p = v; }

// ---------------- fp32 -> bf16 cast (vectorized, n % 1024 == 0) ----------------
__global__ __launch_bounds__(256)
void cast_f2b(const float* __restrict__ X, bf16* __restrict__ Y, long n)
{
    const long i = ((long)blockIdx.x * 256 + threadIdx.x) * 4;
    if (i + 3 < n) {
        const float4 v = *(const float4*)(X + i);
        Y[i + 0] = __float2bfloat16(v.x);
        Y[i + 1] = __float2bfloat16(v.y);
        Y[i + 2] = __float2bfloat16(v.z);
        Y[i + 3] = __float2bfloat16(v.w);
    }
}

// ---------------- GEMM: C[M,N] = epi( A[M,K] @ W[N,K]^T + bias[N] ) ----------------
// A,W bf16; bias,R fp32; C is CT (bf16 or float). ACT: 0 none, 1 exact GELU.
// C may alias R elementwise (each thread reads R[idx] then writes C[idx] once).
// Pipelined single-barrier K-loop with double-buffered LDS + register staging:
//   iter i: issue global loads (tile i+1) -> MFMA on buf[i&1] -> store regs to
//   buf[(i+1)&1] -> barrier.  Hazards: reads of buf[(i+1)&1] happen only after
//   this barrier (RAW ok); stores to buf[i&1] happen in iter i+1 after the same
//   barrier that ends reads of buf[i&1] in iter i (WAR ok). One barrier/iter.
template<int ACT, bool HASRES, typename CT, int K>
__global__ __launch_bounds__(256)
void gemm_bt(const bf16* __restrict__ A, const bf16* __restrict__ W,
             const float* __restrict__ bias, const float* __restrict__ R,
             CT* __restrict__ C, int M, int N)
{
    __shared__ __align__(16) unsigned short sA[2 * 128 * 32];  // 2 bufs x 8 KB
    __shared__ __align__(16) unsigned short sB[2 * 128 * 32];

    const int tid  = threadIdx.x;
    const int lane = tid & 63;
    const int wave = tid >> 6;
    const long row0 = (long)blockIdx.x * 128;
    const long col0 = (long)blockIdx.y * 128;
    const int wm = (wave >> 1) * 64;   // wave's 64-row strip in tile
    const int wn = (wave & 1) * 64;    // wave's 64-col strip in tile
    const int fr = lane & 15;          // fragment row (A) / col (B)
    const int fk = (lane >> 4) * 8;    // fragment k offset

    const f4v fzero = {0.f, 0.f, 0.f, 0.f};
    f4v acc[4][4];
#pragma unroll
    for (int i = 0; i < 4; ++i)
#pragma unroll
        for (int j = 0; j < 4; ++j) acc[i][j] = fzero;

    // staging: thread t owns 16B chunk (row = tid>>2, kc = tid&3), rows +0/+64.
    // (tid>>2)*32 + (tid&3)*8 == tid*8 -> lane-contiguous b128 LDS stores.
    const unsigned short* gA = (const unsigned short*)A + (row0 + (tid >> 2)) * (long)K + (tid & 3) * 8;
    const unsigned short* gB = (const unsigned short*)W + (col0 + (tid >> 2)) * (long)K + (tid & 3) * 8;

    // prologue: tile 0 -> buf 0
    {
        const us8 a0 = *(const us8*)(gA);
        const us8 a1 = *(const us8*)(gA + 64 * (long)K);
        const us8 b0 = *(const us8*)(gB);
        const us8 b1 = *(const us8*)(gB + 64 * (long)K);
        *(us8*)&sA[tid * 8]        = a0;
        *(us8*)&sA[2048 + tid * 8] = a1;
        *(us8*)&sB[tid * 8]        = b0;
        *(us8*)&sB[2048 + tid * 8] = b1;
    }
    __syncthreads();

    constexpr int NI = K >> 5;
#pragma unroll 2
    for (int i = 0; i < NI; ++i) {
        us8 a0, a1, b0, b1;
        if (i + 1 < NI) {                       // wave-uniform branch
            const int kn = (i + 1) << 5;
            a0 = *(const us8*)(gA + kn);
            a1 = *(const us8*)(gA + 64 * (long)K + kn);
            b0 = *(const us8*)(gB + kn);
            b1 = *(const us8*)(gB + 64 * (long)K + kn);
        }

        const int base = (i & 1) * 4096;
        bf8v af[4], bv[4];
#pragma unroll
        for (int t = 0; t < 4; ++t) {
            af[t] = *(const bf8v*)&sA[base + (wm + t * 16 + fr) * 32 + fk];
            bv[t] = *(const bf8v*)&sB[base + (wn + t * 16 + fr) * 32 + fk];
        }
#pragma unroll
        for (int ii = 0; ii < 4; ++ii)
#pragma unroll
            for (int jj = 0; jj < 4; ++jj)
                acc[ii][jj] = __builtin_amdgcn_mfma_f32_16x16x32_bf16(af[ii], bv[jj], acc[ii][jj], 0, 0, 0);

        if (i + 1 < NI) {
            const int nb = ((i + 1) & 1) * 4096;
            *(us8*)&sA[nb + tid * 8]        = a0;
            *(us8*)&sA[nb + 2048 + tid * 8] = a1;
            *(us8*)&sB[nb + tid * 8]        = b0;
            *(us8*)&sB[nb + 2048 + tid * 8] = b1;
        }
        __syncthreads();
    }

    // epilogue: D mapping col = lane&15, row = (lane>>4)*4 + reg  [m89/m91 verified]
#pragma unroll
    for (int j = 0; j < 4; ++j) {
        const long n = col0 + wn + j * 16 + fr;
        const float bvv = bias[n];
#pragma unroll
        for (int i = 0; i < 4; ++i) {
            const long mbase = row0 + wm + i * 16 + (lane >> 4) * 4;
#pragma unroll
            for (int r = 0; r < 4; ++r) {
                float v0 = acc[i][j][r] + bvv;
                if (HASRES) v0 += R[(mbase + r) * (long)N + n];
                if (ACT == 1) v0 = 0.5f * v0 * (1.f + erff(v0 * 0.70710678118654752f));
                storeC(&C[(mbase + r) * (long)N + n], v0);
            }
        }
    }
}

// ---------------- per-position head attention (the einsum quirk) ----------------
// For each (b,j): E = Q_j K_j^T / 32 over heads (16x16), softmax rows, O = A V_j (16x64).
// Store with reshape scramble: scr[b, h*128 + j/16, (j%16)*64 + d] = O[h][d].
__global__ __launch_bounds__(256)
void attn_kernel(const bf16* __restrict__ qkv, bf16* __restrict__ scr)
{
    __shared__ float sb[4][3392];   // per wave: q[16][65], k[16][65], v[16][65], a[16][17]
    const int tid = threadIdx.x;
    const int wave = tid >> 6, lane = tid & 63;
    const int m = blockIdx.x * 4 + wave;       // global position in [0, 8192)

    float* q = sb[wave];
    float* k = q + 1040;
    float* v = k + 1040;
    float* a = v + 1040;

    const bf16* rowp = qkv + (size_t)m * 3072;
    for (int i = lane; i < 1024; i += 64) {
        int hh = i >> 6, dd = i & 63;
        q[hh * 65 + dd] = __bfloat162float(rowp[i]);
        k[hh * 65 + dd] = __bfloat162float(rowp[1024 + i]);
        v[hh * 65 + dd] = __bfloat162float(rowp[2048 + i]);
    }
    __syncthreads();

    // lane -> (h1 = lane&15, quad = lane>>4 owning h2 = quad*4..+3)
    const int h1 = lane & 15, qd = lane >> 4;
    float e[4];
#pragma unroll
    for (int j = 0; j < 4; ++j) {
        const float* qr = q + h1 * 65;
        const float* kr = k + (qd * 4 + j) * 65;
        float s0 = 0.f;
        for (int d = 0; d < 64; ++d) s0 += qr[d] * kr[d];
        e[j] = s0 * 0.03125f;                  // 1/sqrt(1024)
    }
    float mx = fmaxf(fmaxf(e[0], e[1]), fmaxf(e[2], e[3]));
    mx = fmaxf(mx, __shfl_xor(mx, 16, 64));
    mx = fmaxf(mx, __shfl_xor(mx, 32, 64));
    float p[4], ps = 0.f;
#pragma unroll
    for (int j = 0; j < 4; ++j) { p[j] = expf(e[j] - mx); ps += p[j]; }
    ps += __shfl_xor(ps, 16, 64);
    ps += __shfl_xor(ps, 32, 64);
    const float inv = 1.f / ps;
#pragma unroll
    for (int j = 0; j < 4; ++j) a[h1 * 17 + qd * 4 + j] = p[j] * inv;
    __syncthreads();

    // O[h][d] = sum_l a[h][l] * v[l][d]; lane -> (h = lane&15, d in (lane>>4)*16..+16)
    const int h = lane & 15, dg = lane >> 4;
    float arow[16];
#pragma unroll
    for (int l2 = 0; l2 < 16; ++l2) arow[l2] = a[h * 17 + l2];
    const int b = m >> 11, j = m & 2047;
    bf16* op = scr + (((size_t)b * 2048 + h * 128 + (j >> 4)) * 1024 + (j & 15) * 64);
    for (int t = 0; t < 16; ++t) {
        const int d = dg * 16 + t;
        float o = 0.f;
#pragma unroll
        for (int l2 = 0; l2 < 16; ++l2) o += arow[l2] * v[l2 * 65 + d];
        op[d] = __float2bfloat16(o);
    }
}

// -------- row LayerNorm over E=1024, fp32 in, fp32 out (+optional bf16 copy) --------
// In-place safe (X==Y32): all loads precede the first barrier within a block's row.
__global__ __launch_bounds__(256)
void ln_kernel(const float* __restrict__ X, const float* __restrict__ G,
               const float* __restrict__ Bt, float* __restrict__ Y32,
               bf16* __restrict__ Yb)
{
    __shared__ float rs[4], rq[4];
    const int tid = threadIdx.x;
    const long row = blockIdx.x;
    const float* xp = X + row * 1024;
    float x[4];
#pragma unroll
    for (int i = 0; i < 4; ++i) x[i] = xp[tid + 256 * i];

    float s = x[0] + x[1] + x[2] + x[3];
#pragma unroll
    for (int off = 32; off; off >>= 1) s += __shfl_down(s, off, 64);
    if ((tid & 63) == 0) rs[tid >> 6] = s;
    __syncthreads();
    const float mean = (rs[0] + rs[1] + rs[2] + rs[3]) * (1.f / 1024.f);

    float qv = 0.f;
#pragma unroll
    for (int i = 0; i < 4; ++i) { float d = x[i] - mean; qv += d * d; }
#pragma unroll
    for (int off = 32; off; off >>= 1) qv += __shfl_down(qv, off, 64);
    if ((tid & 63) == 0) rq[tid >> 6] = qv;
    __syncthreads();
    const float var = (rq[0] + rq[1] + rq[2] + rq[3]) * (1.f / 1024.f);
    const float rstd = rsqrtf(var + 1e-5f);

#pragma unroll
    for (int i = 0; i < 4; ++i) {
        const int e = tid + 256 * i;
        const float yv = (x[i] - mean) * rstd * G[e] + Bt[e];
        Y32[row * 1024 + e] = yv;
        if (Yb) Yb[row * 1024 + e] = __float2bfloat16(yv);
    }
}

extern "C" void kernel_launch(void* const* d_in, const int* in_sizes, int n_in,
                              void* d_out, int out_size, void* d_ws, size_t ws_size,
                              hipStream_t stream)
{
    (void)in_sizes; (void)n_in; (void)out_size;
    // Reference dtypes are all float32.
    const float* x    = (const float*)d_in[0];
    const float* Wqkv = (const float*)d_in[1];
    const float* bqkv = (const float*)d_in[2];
    const float* Wo   = (const float*)d_in[3];
    const float* bo   = (const float*)d_in[4];
    const float* g1   = (const float*)d_in[5];
    const float* b1   = (const float*)d_in[6];
    const float* W1   = (const float*)d_in[7];
    const float* bf1  = (const float*)d_in[8];
    const float* W2   = (const float*)d_in[9];
    const float* bf2  = (const float*)d_in[10];
    const float* g2   = (const float*)d_in[11];
    const float* b2   = (const float*)d_in[12];
    float* out = (float*)d_out;   // fp32 output, also used as h/s2 scratch

    // If ws is too small, bail -> output stays 0 -> absmax == 5.1875 (diagnostic).
    if (ws_size < 125829120ULL) return;

    // ws layout (bytes):
    //   R1 @0, 67,108,864: qkv bf16(50.3M) -> t fp32(33.5M) -> u bf16(67M)
    //   Wqkvb @67108864 (6.3M) | Wob @73400320 (2.1M) | W1b @75497472 (8.4M)
    //   W2b @83886080 (8.4M)   | xb/scr @92274688 (16.8M) | hb @109051904 (16.8M)
    char* ws = (char*)d_ws;
    bf16* qkv   = (bf16*)(ws + 0);
    float* t    = (float*)(ws + 0);
    bf16* u     = (bf16*)(ws + 0);
    bf16* Wqkvb = (bf16*)(ws + 67108864);
    bf16* Wob   = (bf16*)(ws + 73400320);
    bf16* W1b   = (bf16*)(ws + 75497472);
    bf16* W2b   = (bf16*)(ws + 83886080);
    bf16* xb    = (bf16*)(ws + 92274688);
    bf16* scr   = (bf16*)(ws + 92274688);   // reuses xb (dead after gemm1)
    bf16* hb    = (bf16*)(ws + 109051904);
    float* h    = out;                       // fp32 h lives in d_out until gemm6

    // 0) casts fp32 -> bf16
    cast_f2b<<<8192, 256, 0, stream>>>(x,    xb,    8388608);
    cast_f2b<<<3072, 256, 0, stream>>>(Wqkv, Wqkvb, 3145728);
    cast_f2b<<<1024, 256, 0, stream>>>(Wo,   Wob,   1048576);
    cast_f2b<<<4096, 256, 0, stream>>>(W1,   W1b,   4194304);
    cast_f2b<<<4096, 256, 0, stream>>>(W2,   W2b,   4194304);

    // 1) qkv = x @ Wqkv^T + bqkv            (bf16 out)
    gemm_bt<0, false, bf16, 1024><<<dim3(64, 24), 256, 0, stream>>>(xb, Wqkvb, bqkv, nullptr, qkv, 8192, 3072);
    // 2) per-position head attention + reshape scramble -> scr
    attn_kernel<<<2048, 256, 0, stream>>>(qkv, scr);
    // 3) t = scr @ Wo^T + bo + x            (fp32 out, fp32 residual)
    gemm_bt<0, true, float, 1024><<<dim3(64, 8), 256, 0, stream>>>(scr, Wob, bo, x, t, 8192, 1024);
    // 4) h = LN1(t)  -> fp32 h (d_out) + bf16 hb
    ln_kernel<<<8192, 256, 0, stream>>>(t, g1, b1, h, hb);
    // 5) u = gelu(hb @ W1^T + bf1)          (bf16 out, overwrites R1; t is dead)
    gemm_bt<1, false, bf16, 1024><<<dim3(64, 32), 256, 0, stream>>>(hb, W1b, bf1, nullptr, u, 8192, 4096);
    // 6) s2 = u @ W2^T + bf2 + h            (fp32 out aliasing R=h elementwise in d_out)
    gemm_bt<0, true, float, 4096><<<dim3(64, 8), 256, 0, stream>>>(u, W2b, bf2, h, out, 8192, 1024);
    // 7) out = LN2(s2) in-place, fp32 only
    ln_kernel<<<8192, 256, 0, stream>>>(out, g2, b2, out, nullptr);
}

// Round 6
// 514.418 us; speedup vs baseline: 1.0484x; 1.0012x over previous
//
#include <hip/hip_runtime.h>
#include <hip/hip_bf16.h>
#include <math.h>

typedef __hip_bfloat16 bf16;
typedef __bf16 bf8v __attribute__((ext_vector_type(8)));
typedef float f4v __attribute__((ext_vector_type(4)));

__device__ inline void storeC(bf16* p, float v) { *p = __float2bfloat16(v); }
__device__ inline void storeC(float* p, float v) { *p = v; }

// async global->LDS, 16B per lane; LDS base must be wave-uniform, HW adds lane*16.
__device__ inline void gld16(const void* g, void* l) {
    __builtin_amdgcn_global_load_lds(
        (__attribute__((address_space(1))) void*)g,
        (__attribute__((address_space(3))) void*)l, 16, 0, 0);
}

// ---------------- fp32 -> bf16 cast (vectorized, n % 1024 == 0) ----------------
__global__ __launch_bounds__(256)
void cast_f2b(const float* __restrict__ X, bf16* __restrict__ Y, long n)
{
    const long i = ((long)blockIdx.x * 256 + threadIdx.x) * 4;
    if (i + 3 < n) {
        const float4 v = *(const float4*)(X + i);
        Y[i + 0] = __float2bfloat16(v.x);
        Y[i + 1] = __float2bfloat16(v.y);
        Y[i + 2] = __float2bfloat16(v.z);
        Y[i + 3] = __float2bfloat16(v.w);
    }
}

// ---------------- GEMM: C[M,N] = epi( A[M,K] @ W[N,K]^T + bias[N] ) ----------------
// A,W bf16; bias,R fp32; C is CT (bf16 or float). ACT: 0 none, 1 exact GELU.
// C may alias R elementwise (each thread reads R[idx] then writes C[idx] once).
// Pipelined single-barrier K-loop, double-buffered LDS, global_load_lds staging:
//   iter i: issue gld16 for tile i+1 -> buf[(i+1)&1]  (async, no regs)
//           ds_read + 16 MFMA on buf[i&1]             (~200 cyc of cover)
//           __syncthreads()  (drains vmcnt -> buf[(i+1)&1] ready; also closes
//                             reads of buf[i&1] before iter i+1 overwrites it... 
//                             note buf[i&1] is only rewritten at iter i+2, so WAR
//                             distance is TWO barriers - safe.)
template<int ACT, bool HASRES, typename CT, int K>
__global__ __launch_bounds__(256)
void gemm_bt(const bf16* __restrict__ A, const bf16* __restrict__ W,
             const float* __restrict__ bias, const float* __restrict__ R,
             CT* __restrict__ C, int M, int N)
{
    __shared__ __align__(16) unsigned short sA[2 * 128 * 32];  // 2 bufs x 8 KB
    __shared__ __align__(16) unsigned short sB[2 * 128 * 32];

    const int tid  = threadIdx.x;
    const int lane = tid & 63;
    const int wave = tid >> 6;
    const long row0 = (long)blockIdx.x * 128;
    const long col0 = (long)blockIdx.y * 128;
    const int wm = (wave >> 1) * 64;   // wave's 64-row strip in tile
    const int wn = (wave & 1) * 64;    // wave's 64-col strip in tile
    const int fr = lane & 15;          // fragment row (A) / col (B)
    const int fk = (lane >> 4) * 8;    // fragment k offset

    const f4v fzero = {0.f, 0.f, 0.f, 0.f};
    f4v acc[4][4];
#pragma unroll
    for (int i = 0; i < 4; ++i)
#pragma unroll
        for (int j = 0; j < 4; ++j) acc[i][j] = fzero;

    // staging: thread t owns 16B chunk (row = tid>>2, kc = tid&3), rows +0/+64.
    // (tid>>2)*32 + (tid&3)*8 == tid*8 -> LDS dest is lane-contiguous, matching
    // gld16's wave-uniform-base + lane*16B write pattern (wave w base = w*512 shorts).
    const unsigned short* gA = (const unsigned short*)A + (row0 + (tid >> 2)) * (long)K + (tid & 3) * 8;
    const unsigned short* gB = (const unsigned short*)W + (col0 + (tid >> 2)) * (long)K + (tid & 3) * 8;
    unsigned short* lA0 = &sA[wave * 512];
    unsigned short* lA1 = &sA[2048 + wave * 512];
    unsigned short* lB0 = &sB[wave * 512];
    unsigned short* lB1 = &sB[2048 + wave * 512];

    // prologue: tile 0 -> buf 0 (barrier drains vmcnt)
    gld16(gA,                lA0);
    gld16(gA + 64 * (long)K, lA1);
    gld16(gB,                lB0);
    gld16(gB + 64 * (long)K, lB1);
    __syncthreads();

    constexpr int NI = K >> 5;
#pragma unroll 2
    for (int i = 0; i < NI; ++i) {
        if (i + 1 < NI) {                       // wave-uniform branch
            const int kn = (i + 1) << 5;
            const int nb = ((i + 1) & 1) * 4096;
            gld16(gA + kn,                lA0 + nb);
            gld16(gA + 64 * (long)K + kn, lA1 + nb);
            gld16(gB + kn,                lB0 + nb);
            gld16(gB + 64 * (long)K + kn, lB1 + nb);
        }

        const int base = (i & 1) * 4096;
        bf8v af[4], bv[4];
#pragma unroll
        for (int t = 0; t < 4; ++t) {
            af[t] = *(const bf8v*)&sA[base + (wm + t * 16 + fr) * 32 + fk];
            bv[t] = *(const bf8v*)&sB[base + (wn + t * 16 + fr) * 32 + fk];
        }
#pragma unroll
        for (int ii = 0; ii < 4; ++ii)
#pragma unroll
            for (int jj = 0; jj < 4; ++jj)
                acc[ii][jj] = __builtin_amdgcn_mfma_f32_16x16x32_bf16(af[ii], bv[jj], acc[ii][jj], 0, 0, 0);

        __syncthreads();   // next buf ready; this buf's reads closed (rewrite at i+2)
    }

    // epilogue: D mapping col = lane&15, row = (lane>>4)*4 + reg  [m89/m91 verified]
#pragma unroll
    for (int j = 0; j < 4; ++j) {
        const long n = col0 + wn + j * 16 + fr;
        const float bvv = bias[n];
#pragma unroll
        for (int i = 0; i < 4; ++i) {
            const long mbase = row0 + wm + i * 16 + (lane >> 4) * 4;
#pragma unroll
            for (int r = 0; r < 4; ++r) {
                float v0 = acc[i][j][r] + bvv;
                if (HASRES) v0 += R[(mbase + r) * (long)N + n];
                if (ACT == 1) v0 = 0.5f * v0 * (1.f + erff(v0 * 0.70710678118654752f));
                storeC(&C[(mbase + r) * (long)N + n], v0);
            }
        }
    }
}

// ---------------- per-position head attention (the einsum quirk) ----------------
// For each (b,j): E = Q_j K_j^T / 32 over heads (16x16), softmax rows, O = A V_j (16x64).
// Store with reshape scramble: scr[b, h*128 + j/16, (j%16)*64 + d] = O[h][d].
__global__ __launch_bounds__(256)
void attn_kernel(const bf16* __restrict__ qkv, bf16* __restrict__ scr)
{
    __shared__ float sb[4][3392];   // per wave: q[16][65], k[16][65], v[16][65], a[16][17]
    const int tid = threadIdx.x;
    const int wave = tid >> 6, lane = tid & 63;
    const int m = blockIdx.x * 4 + wave;       // global position in [0, 8192)

    float* q = sb[wave];
    float* k = q + 1040;
    float* v = k + 1040;
    float* a = v + 1040;

    const bf16* rowp = qkv + (size_t)m * 3072;
    for (int i = lane; i < 1024; i += 64) {
        int hh = i >> 6, dd = i & 63;
        q[hh * 65 + dd] = __bfloat162float(rowp[i]);
        k[hh * 65 + dd] = __bfloat162float(rowp[1024 + i]);
        v[hh * 65 + dd] = __bfloat162float(rowp[2048 + i]);
    }
    __syncthreads();

    // lane -> (h1 = lane&15, quad = lane>>4 owning h2 = quad*4..+3)
    const int h1 = lane & 15, qd = lane >> 4;
    float e[4];
#pragma unroll
    for (int j = 0; j < 4; ++j) {
        const float* qr = q + h1 * 65;
        const float* kr = k + (qd * 4 + j) * 65;
        float s0 = 0.f;
        for (int d = 0; d < 64; ++d) s0 += qr[d] * kr[d];
        e[j] = s0 * 0.03125f;                  // 1/sqrt(1024)
    }
    float mx = fmaxf(fmaxf(e[0], e[1]), fmaxf(e[2], e[3]));
    mx = fmaxf(mx, __shfl_xor(mx, 16, 64));
    mx = fmaxf(mx, __shfl_xor(mx, 32, 64));
    float p[4], ps = 0.f;
#pragma unroll
    for (int j = 0; j < 4; ++j) { p[j] = expf(e[j] - mx); ps += p[j]; }
    ps += __shfl_xor(ps, 16, 64);
    ps += __shfl_xor(ps, 32, 64);
    const float inv = 1.f / ps;
#pragma unroll
    for (int j = 0; j < 4; ++j) a[h1 * 17 + qd * 4 + j] = p[j] * inv;
    __syncthreads();

    // O[h][d] = sum_l a[h][l] * v[l][d]; lane -> (h = lane&15, d in (lane>>4)*16..+16)
    const int h = lane & 15, dg = lane >> 4;
    float arow[16];
#pragma unroll
    for (int l2 = 0; l2 < 16; ++l2) arow[l2] = a[h * 17 + l2];
    const int b = m >> 11, j = m & 2047;
    bf16* op = scr + (((size_t)b * 2048 + h * 128 + (j >> 4)) * 1024 + (j & 15) * 64);
    for (int t = 0; t < 16; ++t) {
        const int d = dg * 16 + t;
        float o = 0.f;
#pragma unroll
        for (int l2 = 0; l2 < 16; ++l2) o += arow[l2] * v[l2 * 65 + d];
        op[d] = __float2bfloat16(o);
    }
}

// -------- row LayerNorm over E=1024, fp32 in, fp32 out (+optional bf16 copy) --------
// In-place safe (X==Y32): all loads precede the first barrier within a block's row.
__global__ __launch_bounds__(256)
void ln_kernel(const float* __restrict__ X, const float* __restrict__ G,
               const float* __restrict__ Bt, float* __restrict__ Y32,
               bf16* __restrict__ Yb)
{
    __shared__ float rs[4], rq[4];
    const int tid = threadIdx.x;
    const long row = blockIdx.x;
    const float* xp = X + row * 1024;
    float x[4];
#pragma unroll
    for (int i = 0; i < 4; ++i) x[i] = xp[tid + 256 * i];

    float s = x[0] + x[1] + x[2] + x[3];
#pragma unroll
    for (int off = 32; off; off >>= 1) s += __shfl_down(s, off, 64);
    if ((tid & 63) == 0) rs[tid >> 6] = s;
    __syncthreads();
    const float mean = (rs[0] + rs[1] + rs[2] + rs[3]) * (1.f / 1024.f);

    float qv = 0.f;
#pragma unroll
    for (int i = 0; i < 4; ++i) { float d = x[i] - mean; qv += d * d; }
#pragma unroll
    for (int off = 32; off; off >>= 1) qv += __shfl_down(qv, off, 64);
    if ((tid & 63) == 0) rq[tid >> 6] = qv;
    __syncthreads();
    const float var = (rq[0] + rq[1] + rq[2] + rq[3]) * (1.f / 1024.f);
    const float rstd = rsqrtf(var + 1e-5f);

#pragma unroll
    for (int i = 0; i < 4; ++i) {
        const int e = tid + 256 * i;
        const float yv = (x[i] - mean) * rstd * G[e] + Bt[e];
        Y32[row * 1024 + e] = yv;
        if (Yb) Yb[row * 1024 + e] = __float2bfloat16(yv);
    }
}

extern "C" void kernel_launch(void* const* d_in, const int* in_sizes, int n_in,
                              void* d_out, int out_size, void* d_ws, size_t ws_size,
                              hipStream_t stream)
{
    (void)in_sizes; (void)n_in; (void)out_size;
    // Reference dtypes are all float32.
    const float* x    = (const float*)d_in[0];
    const float* Wqkv = (const float*)d_in[1];
    const float* bqkv = (const float*)d_in[2];
    const float* Wo   = (const float*)d_in[3];
    const float* bo   = (const float*)d_in[4];
    const float* g1   = (const float*)d_in[5];
    const float* b1   = (const float*)d_in[6];
    const float* W1   = (const float*)d_in[7];
    const float* bf1  = (const float*)d_in[8];
    const float* W2   = (const float*)d_in[9];
    const float* bf2  = (const float*)d_in[10];
    const float* g2   = (const float*)d_in[11];
    const float* b2   = (const float*)d_in[12];
    float* out = (float*)d_out;   // fp32 output, also used as h/s2 scratch

    // If ws is too small, bail -> output stays 0 -> absmax == 5.1875 (diagnostic).
    if (ws_size < 125829120ULL) return;

    // ws layout (bytes):
    //   R1 @0, 67,108,864: qkv bf16(50.3M) -> t fp32(33.5M) -> u bf16(67M)
    //   Wqkvb @67108864 (6.3M) | Wob @73400320 (2.1M) | W1b @75497472 (8.4M)
    //   W2b @83886080 (8.4M)   | xb/scr @92274688 (16.8M) | hb @109051904 (16.8M)
    char* ws = (char*)d_ws;
    bf16* qkv   = (bf16*)(ws + 0);
    float* t    = (float*)(ws + 0);
    bf16* u     = (bf16*)(ws + 0);
    bf16* Wqkvb = (bf16*)(ws + 67108864);
    bf16* Wob   = (bf16*)(ws + 73400320);
    bf16* W1b   = (bf16*)(ws + 75497472);
    bf16* W2b   = (bf16*)(ws + 83886080);
    bf16* xb    = (bf16*)(ws + 92274688);
    bf16* scr   = (bf16*)(ws + 92274688);   // reuses xb (dead after gemm1)
    bf16* hb    = (bf16*)(ws + 109051904);
    float* h    = out;                       // fp32 h lives in d_out until gemm6

    // 0) casts fp32 -> bf16
    cast_f2b<<<8192, 256, 0, stream>>>(x,    xb,    8388608);
    cast_f2b<<<3072, 256, 0, stream>>>(Wqkv, Wqkvb, 3145728);
    cast_f2b<<<1024, 256, 0, stream>>>(Wo,   Wob,   1048576);
    cast_f2b<<<4096, 256, 0, stream>>>(W1,   W1b,   4194304);
    cast_f2b<<<4096, 256, 0, stream>>>(W2,   W2b,   4194304);

    // 1) qkv = x @ Wqkv^T + bqkv            (bf16 out)
    gemm_bt<0, false, bf16, 1024><<<dim3(64, 24), 256, 0, stream>>>(xb, Wqkvb, bqkv, nullptr, qkv, 8192, 3072);
    // 2) per-position head attention + reshape scramble -> scr
    attn_kernel<<<2048, 256, 0, stream>>>(qkv, scr);
    // 3) t = scr @ Wo^T + bo + x            (fp32 out, fp32 residual)
    gemm_bt<0, true, float, 1024><<<dim3(64, 8), 256, 0, stream>>>(scr, Wob, bo, x, t, 8192, 1024);
    // 4) h = LN1(t)  -> fp32 h (d_out) + bf16 hb
    ln_kernel<<<8192, 256, 0, stream>>>(t, g1, b1, h, hb);
    // 5) u = gelu(hb @ W1^T + bf1)          (bf16 out, overwrites R1; t is dead)
    gemm_bt<1, false, bf16, 1024><<<dim3(64, 32), 256, 0, stream>>>(hb, W1b, bf1, nullptr, u, 8192, 4096);
    // 6) s2 = u @ W2^T + bf2 + h            (fp32 out aliasing R=h elementwise in d_out)
    gemm_bt<0, true, float, 4096><<<dim3(64, 8), 256, 0, stream>>>(u, W2b, bf2, h, out, 8192, 1024);
    // 7) out = LN2(s2) in-place, fp32 only
    ln_kernel<<<8192, 256, 0, stream>>>(out, g2, b2, out, nullptr);
}